// Round 11
// baseline (626.454 us; speedup 1.0000x reference)
//
#include <hip/hip_runtime.h>
#include <hip/hip_cooperative_groups.h>
#include <stdint.h>

namespace cg = cooperative_groups;

#define N_NODES 50000
#define N_EDGES 800000
#define IN_DIM 128
#define HID_DIM 128
#define OUT_DIM 64

#define COOP_BLOCKS 1024
#define COOP_THREADS 256
#define GT (COOP_BLOCKS * COOP_THREADS)     // 262144
#define EPT 4                               // 262144*4 >= 800000

#define NBUCKETS 8
#define ROWS_PER_BKT (N_NODES / NBUCKETS)   // 6250
#define BKT_CAP 104000                      // mean 100k, sigma ~300 -> +13 sigma

#define SCAN_BLOCKS 64
#define SCAN_CH 4                           // 64*256*4 = 65536 >= N_NODES

typedef short bf16x8 __attribute__((ext_vector_type(8)));
typedef float f32x4  __attribute__((ext_vector_type(4)));

__device__ __forceinline__ uint32_t pack_bf16x2(float a, float b) {
    uint32_t ba = __float_as_uint(a), bb = __float_as_uint(b);
    ba = (ba + 0x7fffu + ((ba >> 16) & 1u)) >> 16;           // RNE low half
    bb = (bb + 0x7fffu + ((bb >> 16) & 1u)) & 0xffff0000u;   // RNE high half
    return ba | bb;
}

__device__ __forceinline__ unsigned short f2bf(float f) {
    uint32_t u = __float_as_uint(f);
    return (unsigned short)((u + 0x7fffu + ((u >> 16) & 1u)) >> 16);
}

// CSR entry: high 16 bits = bf16(val), low 16 bits = col (col < 65536)
__device__ __forceinline__ uint32_t pack_edge(int col, float v) {
    uint32_t fb = __float_as_uint(v);
    fb = (fb + 0x7fffu + ((fb >> 16) & 1u)) & 0xffff0000u;
    return fb | (uint32_t)col;
}

// ---------------- cooperative CSR build + weight convert ----------------
// phase 0: zero counts/gcnt, convert W1/W2 -> bf16 transposed
// phase 1: one pass over edges: per-row histogram + append {row,packed} to
//          one of 8 row-range buckets (LDS-aggregated counters)
// phase 2/3: two-level exclusive scan -> row_ptr, cursor
// phase 4: per-bucket scatter; bucket g handled by blocks with (bid&7)==g,
//          dest region ~0.4MB -> L2-local full-line writes

struct BuildArgs {
    const int* row; const int* col; const float* vals;
    const float* W1; const float* W2;
    int* counts; int* row_ptr; int* cursor; int* bsum; int* gcnt;
    unsigned long long* ebuf; uint32_t* csr;
    unsigned short* wt1; unsigned short* wt2;
};

__global__ void __launch_bounds__(COOP_THREADS) coop_build(BuildArgs a) {
    cg::grid_group grid = cg::this_grid();
    const int tid = threadIdx.x;
    const int bid = blockIdx.x;
    const int gtid = bid * COOP_THREADS + tid;

    // ---- phase 0 ----
    if (gtid < N_NODES) a.counts[gtid] = 0;
    if (gtid < NBUCKETS) a.gcnt[gtid] = 0;
    if (gtid < 128 * 128) {
        int n = gtid >> 7, k = gtid & 127;
        a.wt1[gtid] = f2bf(a.W1[k * 128 + n]);
    } else if (gtid < 128 * 128 + 64 * 128) {
        int j = gtid - 128 * 128;
        int n = j >> 7, k = j & 127;
        a.wt2[j] = f2bf(a.W2[k * 64 + n]);
    }
    grid.sync();

    // ---- phase 1: histogram + binning ----
    __shared__ int lcnt[NBUCKETS], lbase[NBUCKETS];
    if (tid < NBUCKETS) lcnt[tid] = 0;
    __syncthreads();
    int gg[EPT], slot[EPT];
    unsigned long long pk[EPT];
#pragma unroll
    for (int k = 0; k < EPT; ++k) {
        int e = gtid + k * GT;
        gg[k] = -1;
        if (e < N_EDGES) {
            int r = a.row[e];
            atomicAdd(&a.counts[r], 1);
            int g = r / ROWS_PER_BKT;
            gg[k] = g;
            slot[k] = atomicAdd(&lcnt[g], 1);
            pk[k] = ((unsigned long long)(unsigned)r << 32) | pack_edge(a.col[e], a.vals[e]);
        }
    }
    __syncthreads();
    if (tid < NBUCKETS) lbase[tid] = atomicAdd(&a.gcnt[tid], lcnt[tid]);
    __syncthreads();
#pragma unroll
    for (int k = 0; k < EPT; ++k) {
        if (gg[k] >= 0)
            a.ebuf[(size_t)gg[k] * BKT_CAP + lbase[gg[k]] + slot[k]] = pk[k];
    }
    grid.sync();

    // ---- phase 2: per-block partial sums (blocks 0..63) ----
    __shared__ int red[COOP_THREADS];
    if (bid < SCAN_BLOCKS) {
        const int base = (bid * COOP_THREADS + tid) * SCAN_CH;
        int s = 0;
#pragma unroll
        for (int i = 0; i < SCAN_CH; ++i) {
            int idx = base + i;
            if (idx < N_NODES) s += a.counts[idx];
        }
        red[tid] = s;
        __syncthreads();
#pragma unroll
        for (int off = COOP_THREADS / 2; off > 0; off >>= 1) {
            if (tid < off) red[tid] += red[tid + off];
            __syncthreads();
        }
        if (tid == 0) a.bsum[bid] = red[0];
    }
    grid.sync();

    // ---- phase 3: rescan + write row_ptr / cursor (blocks 0..63) ----
    __shared__ int sh_boff;
    if (bid < SCAN_BLOCKS) {
        if (tid == 0) {
            int s = 0;
            for (int i = 0; i < bid; ++i) s += a.bsum[i];
            sh_boff = s;
        }
        const int base = (bid * COOP_THREADS + tid) * SCAN_CH;
        int local[SCAN_CH];
        int s = 0;
#pragma unroll
        for (int i = 0; i < SCAN_CH; ++i) {
            int idx = base + i;
            int c = (idx < N_NODES) ? a.counts[idx] : 0;
            local[i] = c;
            s += c;
        }
        red[tid] = s;
        __syncthreads();
#pragma unroll
        for (int off = 1; off < COOP_THREADS; off <<= 1) {
            int v = red[tid];
            int add = (tid >= off) ? red[tid - off] : 0;
            __syncthreads();
            red[tid] = v + add;
            __syncthreads();
        }
        int run = sh_boff + red[tid] - s;
#pragma unroll
        for (int i = 0; i < SCAN_CH; ++i) {
            int idx = base + i;
            if (idx < N_NODES) {
                a.row_ptr[idx] = run;
                a.cursor[idx]  = run;
                run += local[i];
            }
        }
        if (bid == 0 && tid == 0) a.row_ptr[N_NODES] = N_EDGES;
    }
    grid.sync();

    // ---- phase 4: bucket-local scatter ----
    {
        const int g   = bid & (NBUCKETS - 1);
        const int blk = bid >> 3;                       // 0..127
        const int nb  = COOP_BLOCKS / NBUCKETS;         // 128
        const int total = a.gcnt[g];
        const unsigned long long* eb = a.ebuf + (size_t)g * BKT_CAP;
        for (int i = blk * COOP_THREADS + tid; i < total; i += nb * COOP_THREADS) {
            unsigned long long e = eb[i];
            int r = (int)(e >> 32);
            int p = atomicAdd(&a.cursor[r], 1);
            a.csr[p] = (uint32_t)e;
        }
    }
}

// ---------------- MFMA GEMM: outb[M,N](bf16) = A[M,128] @ W[128,N] ----------------
// 16x16x32 bf16 MFMA layouts (HW-verified):
//   A: row=lane&15, k=(lane>>4)*8+j ; B from Wt[n][k]: col=lane&15, same k
//   D: col=lane&15, row=(lane>>4)*4+reg.  50000 rows = 3125 m-tiles exactly.

template<int N, bool AF32>
__global__ __launch_bounds__(256) void gemm_mfma(const float* __restrict__ Af,
                                                 const uint32_t* __restrict__ Apk,
                                                 const unsigned short* __restrict__ Wt,
                                                 unsigned short* __restrict__ outb) {
    const int tid = threadIdx.x;
    const int wid = tid >> 6, lane = tid & 63;
    const int l15 = lane & 15, lk = lane >> 4;
    const int n0 = blockIdx.y * 64;

    bf16x8 bfrag[4][4];
#pragma unroll
    for (int t = 0; t < 4; ++t) {
        const unsigned short* wp = Wt + (size_t)(n0 + t * 16 + l15) * 128 + lk * 8;
#pragma unroll
        for (int s = 0; s < 4; ++s)
            bfrag[t][s] = *reinterpret_cast<const bf16x8*>(wp + s * 32);
    }

    for (int mt = blockIdx.x * 4 + wid; mt < 3125; mt += 784) {
        const int row = mt * 16 + l15;
        bf16x8 afrag[4];
        if (AF32) {
            const float* ap = Af + (size_t)row * 128 + lk * 8;
#pragma unroll
            for (int s = 0; s < 4; ++s) {
                float4 p0 = *reinterpret_cast<const float4*>(ap + s * 32);
                float4 p1 = *reinterpret_cast<const float4*>(ap + s * 32 + 4);
                bf16x8 f;
                f[0] = (short)f2bf(p0.x); f[1] = (short)f2bf(p0.y);
                f[2] = (short)f2bf(p0.z); f[3] = (short)f2bf(p0.w);
                f[4] = (short)f2bf(p1.x); f[5] = (short)f2bf(p1.y);
                f[6] = (short)f2bf(p1.z); f[7] = (short)f2bf(p1.w);
                afrag[s] = f;
            }
        } else {
            const uint32_t* ap = Apk + (size_t)row * 64 + lk * 4;
#pragma unroll
            for (int s = 0; s < 4; ++s)
                afrag[s] = *reinterpret_cast<const bf16x8*>(ap + s * 16);
        }

        f32x4 acc[4] = {{0.f,0.f,0.f,0.f},{0.f,0.f,0.f,0.f},{0.f,0.f,0.f,0.f},{0.f,0.f,0.f,0.f}};
#pragma unroll
        for (int s = 0; s < 4; ++s)
#pragma unroll
            for (int t = 0; t < 4; ++t)
                acc[t] = __builtin_amdgcn_mfma_f32_16x16x32_bf16(afrag[s], bfrag[t][s], acc[t], 0, 0, 0);

#pragma unroll
        for (int t = 0; t < 4; ++t)
#pragma unroll
            for (int q = 0; q < 4; ++q) {
                int r = mt * 16 + lk * 4 + q;
                outb[(size_t)r * N + n0 + t * 16 + l15] = f2bf(acc[t][q]);
            }
    }
}

// ---------------- CSR SPMM over bf16-packed operand, f32 accumulate ----------------

// D=128: xp is [N][64] packed bf16x2; lane = dims {2l,2l+1}; 8-deep + 4-deep tail.
template<bool RELU>
__global__ __launch_bounds__(256) void spmm_bf16_128(const int* __restrict__ row_ptr,
                                                     const uint32_t* __restrict__ csr,
                                                     const uint32_t* __restrict__ xp,
                                                     uint32_t* __restrict__ outp) {
    const int wid = threadIdx.x >> 6;
    const int lane = threadIdx.x & 63;
    const int r = blockIdx.x * 4 + wid;
    if (r >= N_NODES) return;
    const int start = row_ptr[r];
    const int end   = row_ptr[r + 1];
    const uint32_t* xb = xp + lane;

    float alo[4] = {0.f, 0.f, 0.f, 0.f};
    float ahi[4] = {0.f, 0.f, 0.f, 0.f};
    int e = start;
    for (; e + 7 < end; e += 8) {
        uint32_t c0 = csr[e],     c1 = csr[e + 1], c2 = csr[e + 2], c3 = csr[e + 3];
        uint32_t c4 = csr[e + 4], c5 = csr[e + 5], c6 = csr[e + 6], c7 = csr[e + 7];
        uint32_t u0 = xb[(size_t)(c0 & 0xffffu) * 64];
        uint32_t u1 = xb[(size_t)(c1 & 0xffffu) * 64];
        uint32_t u2 = xb[(size_t)(c2 & 0xffffu) * 64];
        uint32_t u3 = xb[(size_t)(c3 & 0xffffu) * 64];
        uint32_t u4 = xb[(size_t)(c4 & 0xffffu) * 64];
        uint32_t u5 = xb[(size_t)(c5 & 0xffffu) * 64];
        uint32_t u6 = xb[(size_t)(c6 & 0xffffu) * 64];
        uint32_t u7 = xb[(size_t)(c7 & 0xffffu) * 64];
        float v0 = __uint_as_float(c0 & 0xffff0000u), v1 = __uint_as_float(c1 & 0xffff0000u);
        float v2 = __uint_as_float(c2 & 0xffff0000u), v3 = __uint_as_float(c3 & 0xffff0000u);
        float v4 = __uint_as_float(c4 & 0xffff0000u), v5 = __uint_as_float(c5 & 0xffff0000u);
        float v6 = __uint_as_float(c6 & 0xffff0000u), v7 = __uint_as_float(c7 & 0xffff0000u);
        alo[0] = fmaf(v0, __uint_as_float(u0 << 16), alo[0]);
        ahi[0] = fmaf(v0, __uint_as_float(u0 & 0xffff0000u), ahi[0]);
        alo[1] = fmaf(v1, __uint_as_float(u1 << 16), alo[1]);
        ahi[1] = fmaf(v1, __uint_as_float(u1 & 0xffff0000u), ahi[1]);
        alo[2] = fmaf(v2, __uint_as_float(u2 << 16), alo[2]);
        ahi[2] = fmaf(v2, __uint_as_float(u2 & 0xffff0000u), ahi[2]);
        alo[3] = fmaf(v3, __uint_as_float(u3 << 16), alo[3]);
        ahi[3] = fmaf(v3, __uint_as_float(u3 & 0xffff0000u), ahi[3]);
        alo[0] = fmaf(v4, __uint_as_float(u4 << 16), alo[0]);
        ahi[0] = fmaf(v4, __uint_as_float(u4 & 0xffff0000u), ahi[0]);
        alo[1] = fmaf(v5, __uint_as_float(u5 << 16), alo[1]);
        ahi[1] = fmaf(v5, __uint_as_float(u5 & 0xffff0000u), ahi[1]);
        alo[2] = fmaf(v6, __uint_as_float(u6 << 16), alo[2]);
        ahi[2] = fmaf(v6, __uint_as_float(u6 & 0xffff0000u), ahi[2]);
        alo[3] = fmaf(v7, __uint_as_float(u7 << 16), alo[3]);
        ahi[3] = fmaf(v7, __uint_as_float(u7 & 0xffff0000u), ahi[3]);
    }
    if (e + 3 < end) {
        uint32_t c0 = csr[e], c1 = csr[e + 1], c2 = csr[e + 2], c3 = csr[e + 3];
        uint32_t u0 = xb[(size_t)(c0 & 0xffffu) * 64];
        uint32_t u1 = xb[(size_t)(c1 & 0xffffu) * 64];
        uint32_t u2 = xb[(size_t)(c2 & 0xffffu) * 64];
        uint32_t u3 = xb[(size_t)(c3 & 0xffffu) * 64];
        float v0 = __uint_as_float(c0 & 0xffff0000u), v1 = __uint_as_float(c1 & 0xffff0000u);
        float v2 = __uint_as_float(c2 & 0xffff0000u), v3 = __uint_as_float(c3 & 0xffff0000u);
        alo[0] = fmaf(v0, __uint_as_float(u0 << 16), alo[0]);
        ahi[0] = fmaf(v0, __uint_as_float(u0 & 0xffff0000u), ahi[0]);
        alo[1] = fmaf(v1, __uint_as_float(u1 << 16), alo[1]);
        ahi[1] = fmaf(v1, __uint_as_float(u1 & 0xffff0000u), ahi[1]);
        alo[2] = fmaf(v2, __uint_as_float(u2 << 16), alo[2]);
        ahi[2] = fmaf(v2, __uint_as_float(u2 & 0xffff0000u), ahi[2]);
        alo[3] = fmaf(v3, __uint_as_float(u3 << 16), alo[3]);
        ahi[3] = fmaf(v3, __uint_as_float(u3 & 0xffff0000u), ahi[3]);
        e += 4;
    }
    for (; e < end; ++e) {
        uint32_t c0 = csr[e];
        float v0 = __uint_as_float(c0 & 0xffff0000u);
        uint32_t u0 = xb[(size_t)(c0 & 0xffffu) * 64];
        alo[0] = fmaf(v0, __uint_as_float(u0 << 16), alo[0]);
        ahi[0] = fmaf(v0, __uint_as_float(u0 & 0xffff0000u), ahi[0]);
    }
    float rlo = (alo[0] + alo[1]) + (alo[2] + alo[3]);
    float rhi = (ahi[0] + ahi[1]) + (ahi[2] + ahi[3]);
    if (RELU) { rlo = fmaxf(rlo, 0.f); rhi = fmaxf(rhi, 0.f); }
    outp[(size_t)r * 64 + lane] = pack_bf16x2(rlo, rhi);
}

// D=64: xp is [N][32] packed bf16x2; half-wave per edge, 4-deep unroll per half
__global__ __launch_bounds__(256) void spmm_bf16_64(const int* __restrict__ row_ptr,
                                                    const uint32_t* __restrict__ csr,
                                                    const uint32_t* __restrict__ xp,
                                                    float* __restrict__ out) {
    const int wid = threadIdx.x >> 6;
    const int lane = threadIdx.x & 63;
    const int r = blockIdx.x * 4 + wid;
    if (r >= N_NODES) return;
    const int start = row_ptr[r];
    const int end   = row_ptr[r + 1];
    const int j = lane & 31;
    const int half = lane >> 5;
    const uint32_t* xb = xp + j;

    float alo[4] = {0.f, 0.f, 0.f, 0.f};
    float ahi[4] = {0.f, 0.f, 0.f, 0.f};
    int e = start + half;
    for (; e + 6 < end; e += 8) {
        uint32_t c0 = csr[e], c1 = csr[e + 2], c2 = csr[e + 4], c3 = csr[e + 6];
        uint32_t u0 = xb[(size_t)(c0 & 0xffffu) * 32];
        uint32_t u1 = xb[(size_t)(c1 & 0xffffu) * 32];
        uint32_t u2 = xb[(size_t)(c2 & 0xffffu) * 32];
        uint32_t u3 = xb[(size_t)(c3 & 0xffffu) * 32];
        float v0 = __uint_as_float(c0 & 0xffff0000u), v1 = __uint_as_float(c1 & 0xffff0000u);
        float v2 = __uint_as_float(c2 & 0xffff0000u), v3 = __uint_as_float(c3 & 0xffff0000u);
        alo[0] = fmaf(v0, __uint_as_float(u0 << 16), alo[0]);
        ahi[0] = fmaf(v0, __uint_as_float(u0 & 0xffff0000u), ahi[0]);
        alo[1] = fmaf(v1, __uint_as_float(u1 << 16), alo[1]);
        ahi[1] = fmaf(v1, __uint_as_float(u1 & 0xffff0000u), ahi[1]);
        alo[2] = fmaf(v2, __uint_as_float(u2 << 16), alo[2]);
        ahi[2] = fmaf(v2, __uint_as_float(u2 & 0xffff0000u), ahi[2]);
        alo[3] = fmaf(v3, __uint_as_float(u3 << 16), alo[3]);
        ahi[3] = fmaf(v3, __uint_as_float(u3 & 0xffff0000u), ahi[3]);
    }
    for (; e < end; e += 2) {
        uint32_t c0 = csr[e];
        float v = __uint_as_float(c0 & 0xffff0000u);
        uint32_t u = xb[(size_t)(c0 & 0xffffu) * 32];
        alo[0] = fmaf(v, __uint_as_float(u << 16), alo[0]);
        ahi[0] = fmaf(v, __uint_as_float(u & 0xffff0000u), ahi[0]);
    }
    float alo_s = (alo[0] + alo[1]) + (alo[2] + alo[3]);
    float ahi_s = (ahi[0] + ahi[1]) + (ahi[2] + ahi[3]);
    alo_s += __shfl_xor(alo_s, 32);
    ahi_s += __shfl_xor(ahi_s, 32);
    if (half == 0) {
        float2 res = {alo_s, ahi_s};
        *reinterpret_cast<float2*>(out + (size_t)r * 64 + j * 2) = res;
    }
}

// ---------------- launch ----------------

extern "C" void kernel_launch(void* const* d_in, const int* in_sizes, int n_in,
                              void* d_out, int out_size, void* d_ws, size_t ws_size,
                              hipStream_t stream) {
    const float* x    = (const float*)d_in[0];
    const int*   row  = (const int*)  d_in[1];
    const int*   col  = (const int*)  d_in[2];
    const float* vals = (const float*)d_in[3];
    const float* W1   = (const float*)d_in[4];
    const float* W2   = (const float*)d_in[5];
    float* out = (float*)d_out;

    // workspace layout (256B-aligned chunks)
    char* ws = (char*)d_ws;
    auto align = [](size_t v) { return (v + 255) & ~(size_t)255; };
    int*      counts  = (int*)ws;              ws += align(sizeof(int) * N_NODES);
    int*      row_ptr = (int*)ws;              ws += align(sizeof(int) * (N_NODES + 1));
    int*      cursor  = (int*)ws;              ws += align(sizeof(int) * N_NODES);
    int*      bsum    = (int*)ws;              ws += align(sizeof(int) * SCAN_BLOCKS);
    int*      gcnt    = (int*)ws;              ws += align(sizeof(int) * NBUCKETS);
    unsigned long long* ebuf = (unsigned long long*)ws;
                                               ws += align(sizeof(unsigned long long) * NBUCKETS * BKT_CAP);
    uint32_t* csr     = (uint32_t*)ws;         ws += align(sizeof(uint32_t) * N_EDGES);
    uint32_t* tpk     = (uint32_t*)ws;         ws += align(sizeof(uint32_t) * N_NODES * 64);  // gemm1/gemm2 out
    uint32_t* hpk     = (uint32_t*)ws;         ws += align(sizeof(uint32_t) * N_NODES * 64);  // bf16 h
    unsigned short* wt1 = (unsigned short*)ws; ws += align(sizeof(short) * 128 * 128);
    unsigned short* wt2 = (unsigned short*)ws; ws += align(sizeof(short) * 64 * 128);

    // ---- cooperative CSR build + weight convert (1 dispatch) ----
    BuildArgs ba;
    ba.row = row; ba.col = col; ba.vals = vals; ba.W1 = W1; ba.W2 = W2;
    ba.counts = counts; ba.row_ptr = row_ptr; ba.cursor = cursor;
    ba.bsum = bsum; ba.gcnt = gcnt; ba.ebuf = ebuf; ba.csr = csr;
    ba.wt1 = wt1; ba.wt2 = wt2;
    void* kargs[] = { &ba };
    hipLaunchCooperativeKernel((void*)coop_build, dim3(COOP_BLOCKS), dim3(COOP_THREADS),
                               kargs, 0, stream);

    // ---- layer 1: t1 = bf16(x @ W1); h = bf16(relu(A @ t1)) ----
    gemm_mfma<HID_DIM, true><<<dim3(196, 2), 256, 0, stream>>>(x, nullptr, wt1, (unsigned short*)tpk);
    spmm_bf16_128<true><<<(N_NODES + 3) / 4, 256, 0, stream>>>(row_ptr, csr, tpk, hpk);

    // ---- layer 2: t2 = bf16(h @ W2); out = A @ t2 ----
    gemm_mfma<OUT_DIM, false><<<dim3(196, 1), 256, 0, stream>>>(nullptr, hpk, wt2, (unsigned short*)tpk);
    spmm_bf16_64<<<(N_NODES + 3) / 4, 256, 0, stream>>>(row_ptr, csr, tpk, out);
}

// Round 12
// 174.575 us; speedup vs baseline: 3.5885x; 3.5885x over previous
//
#include <hip/hip_runtime.h>
#include <stdint.h>

#define N_NODES 50000
#define N_EDGES 800000
#define IN_DIM 128
#define HID_DIM 128
#define OUT_DIM 64

#define BIN_BLOCKS 1024
#define GT (BIN_BLOCKS * 256)               // 262144
#define EPT 4                               // 262144*4 >= 800000

#define NBUCKETS 8
#define ROWS_PER_BKT (N_NODES / NBUCKETS)   // 6250
#define BKT_CAP 104000

#define SCAN_BLOCKS 64
#define SCAN_THREADS 256
#define SCAN_CH 4                           // 64*256*4 = 65536 >= N_NODES

typedef short bf16x8 __attribute__((ext_vector_type(8)));
typedef float f32x4  __attribute__((ext_vector_type(4)));

__device__ __forceinline__ uint32_t pack_bf16x2(float a, float b) {
    uint32_t ba = __float_as_uint(a), bb = __float_as_uint(b);
    ba = (ba + 0x7fffu + ((ba >> 16) & 1u)) >> 16;           // RNE low half
    bb = (bb + 0x7fffu + ((bb >> 16) & 1u)) & 0xffff0000u;   // RNE high half
    return ba | bb;
}

__device__ __forceinline__ unsigned short f2bf(float f) {
    uint32_t u = __float_as_uint(f);
    return (unsigned short)((u + 0x7fffu + ((u >> 16) & 1u)) >> 16);
}

// CSR entry: high 16 bits = bf16(val), low 16 bits = col (col < 65536)
__device__ __forceinline__ uint32_t pack_edge(int col, float v) {
    uint32_t fb = __float_as_uint(v);
    fb = (fb + 0x7fffu + ((fb >> 16) & 1u)) & 0xffff0000u;
    return fb | (uint32_t)col;
}

// ---------------- CSR build ----------------

__global__ void zero_ints(int* __restrict__ p, int n) {
    int i = blockIdx.x * blockDim.x + threadIdx.x;
    int stride = gridDim.x * blockDim.x;
    for (; i < n; i += stride) p[i] = 0;
}

// one pass over edges: per-row histogram + append {row, packed} into one of
// 8 row-range buckets (LDS-aggregated block cursors -> contiguous 8B runs)
__global__ __launch_bounds__(256) void bin_edges(const int* __restrict__ row,
                                                 const int* __restrict__ col,
                                                 const float* __restrict__ vals,
                                                 int* __restrict__ counts,
                                                 int* __restrict__ gcnt,
                                                 unsigned long long* __restrict__ ebuf) {
    __shared__ int lcnt[NBUCKETS], lbase[NBUCKETS];
    if (threadIdx.x < NBUCKETS) lcnt[threadIdx.x] = 0;
    __syncthreads();
    const int gtid = blockIdx.x * 256 + threadIdx.x;
    int gg[EPT], slot[EPT];
    unsigned long long pk[EPT];
#pragma unroll
    for (int k = 0; k < EPT; ++k) {
        int e = gtid + k * GT;
        gg[k] = -1;
        if (e < N_EDGES) {
            int r = row[e];
            atomicAdd(&counts[r], 1);
            int g = r / ROWS_PER_BKT;
            gg[k] = g;
            slot[k] = atomicAdd(&lcnt[g], 1);
            pk[k] = ((unsigned long long)(unsigned)r << 32) | pack_edge(col[e], vals[e]);
        }
    }
    __syncthreads();
    if (threadIdx.x < NBUCKETS)
        lbase[threadIdx.x] = atomicAdd(&gcnt[threadIdx.x], lcnt[threadIdx.x]);
    __syncthreads();
#pragma unroll
    for (int k = 0; k < EPT; ++k)
        if (gg[k] >= 0)
            ebuf[(size_t)gg[k] * BKT_CAP + lbase[gg[k]] + slot[k]] = pk[k];
}

__global__ __launch_bounds__(SCAN_THREADS) void scan_part(const int* __restrict__ counts,
                                                          int* __restrict__ bsum) {
    __shared__ int red[SCAN_THREADS];
    const int b = blockIdx.x, t = threadIdx.x;
    const int base = (b * SCAN_THREADS + t) * SCAN_CH;
    int s = 0;
#pragma unroll
    for (int i = 0; i < SCAN_CH; ++i) {
        int idx = base + i;
        if (idx < N_NODES) s += counts[idx];
    }
    red[t] = s;
    __syncthreads();
#pragma unroll
    for (int off = SCAN_THREADS / 2; off > 0; off >>= 1) {
        if (t < off) red[t] += red[t + off];
        __syncthreads();
    }
    if (t == 0) bsum[b] = red[0];
}

__global__ __launch_bounds__(SCAN_THREADS) void scan_final(const int* __restrict__ counts,
                                                           const int* __restrict__ bsum,
                                                           int* __restrict__ row_ptr,
                                                           int* __restrict__ cursor) {
    __shared__ int sums[SCAN_THREADS];
    __shared__ int sh_boff;
    const int b = blockIdx.x, t = threadIdx.x;
    if (t == 0) {
        int s = 0;
        for (int i = 0; i < b; ++i) s += bsum[i];
        sh_boff = s;
    }
    const int base = (b * SCAN_THREADS + t) * SCAN_CH;
    int local[SCAN_CH];
    int s = 0;
#pragma unroll
    for (int i = 0; i < SCAN_CH; ++i) {
        int idx = base + i;
        int c = (idx < N_NODES) ? counts[idx] : 0;
        local[i] = c;
        s += c;
    }
    sums[t] = s;
    __syncthreads();
#pragma unroll
    for (int off = 1; off < SCAN_THREADS; off <<= 1) {
        int v = sums[t];
        int add = (t >= off) ? sums[t - off] : 0;
        __syncthreads();
        sums[t] = v + add;
        __syncthreads();
    }
    int run = sh_boff + sums[t] - s;
#pragma unroll
    for (int i = 0; i < SCAN_CH; ++i) {
        int idx = base + i;
        if (idx < N_NODES) {
            row_ptr[idx] = run;
            cursor[idx]  = run;
            run += local[i];
        }
    }
    if (b == 0 && t == 0) row_ptr[N_NODES] = N_EDGES;
}

// per-bucket scatter: bucket g served by blocks with (bid&7)==g; dest region
// ~0.4MB is XCD-L2-local -> full-line writes
__global__ __launch_bounds__(256) void bucket_scatter(const int* __restrict__ gcnt,
                                                      const unsigned long long* __restrict__ ebuf,
                                                      int* __restrict__ cursor,
                                                      uint32_t* __restrict__ csr) {
    const int g   = blockIdx.x & (NBUCKETS - 1);
    const int blk = blockIdx.x >> 3;
    const int nb  = BIN_BLOCKS / NBUCKETS;          // 128 blocks per bucket
    const int total = gcnt[g];
    const unsigned long long* eb = ebuf + (size_t)g * BKT_CAP;
    for (int i = blk * 256 + threadIdx.x; i < total; i += nb * 256) {
        unsigned long long e = eb[i];
        int r = (int)(e >> 32);
        int p = atomicAdd(&cursor[r], 1);
        csr[p] = (uint32_t)e;
    }
}

// ---------------- weights -> bf16 transposed ----------------

__global__ void convert_w_both(const float* __restrict__ W1, const float* __restrict__ W2,
                               unsigned short* __restrict__ wt1, unsigned short* __restrict__ wt2) {
    int i = blockIdx.x * blockDim.x + threadIdx.x;
    if (i < 128 * 128) {
        int n = i >> 7, k = i & 127;
        wt1[i] = f2bf(W1[k * 128 + n]);
    } else if (i < 128 * 128 + 64 * 128) {
        int j = i - 128 * 128;
        int n = j >> 7, k = j & 127;
        wt2[j] = f2bf(W2[k * 64 + n]);
    }
}

// ---------------- MFMA GEMM: outb[M,N](bf16) = A[M,128] @ W[128,N] ----------------
// 16x16x32 bf16 MFMA layouts (HW-verified):
//   A: row=lane&15, k=(lane>>4)*8+j ; B from Wt[n][k]: col=lane&15, same k
//   D: col=lane&15, row=(lane>>4)*4+reg.  50000 rows = 3125 m-tiles exactly.

template<int N, bool AF32>
__global__ __launch_bounds__(256) void gemm_mfma(const float* __restrict__ Af,
                                                 const uint32_t* __restrict__ Apk,
                                                 const unsigned short* __restrict__ Wt,
                                                 unsigned short* __restrict__ outb) {
    const int tid = threadIdx.x;
    const int wid = tid >> 6, lane = tid & 63;
    const int l15 = lane & 15, lk = lane >> 4;
    const int n0 = blockIdx.y * 64;

    bf16x8 bfrag[4][4];
#pragma unroll
    for (int t = 0; t < 4; ++t) {
        const unsigned short* wp = Wt + (size_t)(n0 + t * 16 + l15) * 128 + lk * 8;
#pragma unroll
        for (int s = 0; s < 4; ++s)
            bfrag[t][s] = *reinterpret_cast<const bf16x8*>(wp + s * 32);
    }

    for (int mt = blockIdx.x * 4 + wid; mt < 3125; mt += 784) {
        const int row = mt * 16 + l15;
        bf16x8 afrag[4];
        if (AF32) {
            const float* ap = Af + (size_t)row * 128 + lk * 8;
#pragma unroll
            for (int s = 0; s < 4; ++s) {
                float4 p0 = *reinterpret_cast<const float4*>(ap + s * 32);
                float4 p1 = *reinterpret_cast<const float4*>(ap + s * 32 + 4);
                bf16x8 f;
                f[0] = (short)f2bf(p0.x); f[1] = (short)f2bf(p0.y);
                f[2] = (short)f2bf(p0.z); f[3] = (short)f2bf(p0.w);
                f[4] = (short)f2bf(p1.x); f[5] = (short)f2bf(p1.y);
                f[6] = (short)f2bf(p1.z); f[7] = (short)f2bf(p1.w);
                afrag[s] = f;
            }
        } else {
            const uint32_t* ap = Apk + (size_t)row * 64 + lk * 4;
#pragma unroll
            for (int s = 0; s < 4; ++s)
                afrag[s] = *reinterpret_cast<const bf16x8*>(ap + s * 16);
        }

        f32x4 acc[4] = {{0.f,0.f,0.f,0.f},{0.f,0.f,0.f,0.f},{0.f,0.f,0.f,0.f},{0.f,0.f,0.f,0.f}};
#pragma unroll
        for (int s = 0; s < 4; ++s)
#pragma unroll
            for (int t = 0; t < 4; ++t)
                acc[t] = __builtin_amdgcn_mfma_f32_16x16x32_bf16(afrag[s], bfrag[t][s], acc[t], 0, 0, 0);

#pragma unroll
        for (int t = 0; t < 4; ++t)
#pragma unroll
            for (int q = 0; q < 4; ++q) {
                int r = mt * 16 + lk * 4 + q;
                outb[(size_t)r * N + n0 + t * 16 + l15] = f2bf(acc[t][q]);
            }
    }
}

// ---------------- CSR SPMM over bf16-packed operand, f32 accumulate ----------------

// D=128: xp is [N][64] packed bf16x2; lane = dims {2l,2l+1}; 8-deep + 4-deep tail.
template<bool RELU>
__global__ __launch_bounds__(256) void spmm_bf16_128(const int* __restrict__ row_ptr,
                                                     const uint32_t* __restrict__ csr,
                                                     const uint32_t* __restrict__ xp,
                                                     uint32_t* __restrict__ outp) {
    const int wid = threadIdx.x >> 6;
    const int lane = threadIdx.x & 63;
    const int r = blockIdx.x * 4 + wid;
    if (r >= N_NODES) return;
    const int start = row_ptr[r];
    const int end   = row_ptr[r + 1];
    const uint32_t* xb = xp + lane;

    float alo[4] = {0.f, 0.f, 0.f, 0.f};
    float ahi[4] = {0.f, 0.f, 0.f, 0.f};
    int e = start;
    for (; e + 7 < end; e += 8) {
        uint32_t c0 = csr[e],     c1 = csr[e + 1], c2 = csr[e + 2], c3 = csr[e + 3];
        uint32_t c4 = csr[e + 4], c5 = csr[e + 5], c6 = csr[e + 6], c7 = csr[e + 7];
        uint32_t u0 = xb[(size_t)(c0 & 0xffffu) * 64];
        uint32_t u1 = xb[(size_t)(c1 & 0xffffu) * 64];
        uint32_t u2 = xb[(size_t)(c2 & 0xffffu) * 64];
        uint32_t u3 = xb[(size_t)(c3 & 0xffffu) * 64];
        uint32_t u4 = xb[(size_t)(c4 & 0xffffu) * 64];
        uint32_t u5 = xb[(size_t)(c5 & 0xffffu) * 64];
        uint32_t u6 = xb[(size_t)(c6 & 0xffffu) * 64];
        uint32_t u7 = xb[(size_t)(c7 & 0xffffu) * 64];
        float v0 = __uint_as_float(c0 & 0xffff0000u), v1 = __uint_as_float(c1 & 0xffff0000u);
        float v2 = __uint_as_float(c2 & 0xffff0000u), v3 = __uint_as_float(c3 & 0xffff0000u);
        float v4 = __uint_as_float(c4 & 0xffff0000u), v5 = __uint_as_float(c5 & 0xffff0000u);
        float v6 = __uint_as_float(c6 & 0xffff0000u), v7 = __uint_as_float(c7 & 0xffff0000u);
        alo[0] = fmaf(v0, __uint_as_float(u0 << 16), alo[0]);
        ahi[0] = fmaf(v0, __uint_as_float(u0 & 0xffff0000u), ahi[0]);
        alo[1] = fmaf(v1, __uint_as_float(u1 << 16), alo[1]);
        ahi[1] = fmaf(v1, __uint_as_float(u1 & 0xffff0000u), ahi[1]);
        alo[2] = fmaf(v2, __uint_as_float(u2 << 16), alo[2]);
        ahi[2] = fmaf(v2, __uint_as_float(u2 & 0xffff0000u), ahi[2]);
        alo[3] = fmaf(v3, __uint_as_float(u3 << 16), alo[3]);
        ahi[3] = fmaf(v3, __uint_as_float(u3 & 0xffff0000u), ahi[3]);
        alo[0] = fmaf(v4, __uint_as_float(u4 << 16), alo[0]);
        ahi[0] = fmaf(v4, __uint_as_float(u4 & 0xffff0000u), ahi[0]);
        alo[1] = fmaf(v5, __uint_as_float(u5 << 16), alo[1]);
        ahi[1] = fmaf(v5, __uint_as_float(u5 & 0xffff0000u), ahi[1]);
        alo[2] = fmaf(v6, __uint_as_float(u6 << 16), alo[2]);
        ahi[2] = fmaf(v6, __uint_as_float(u6 & 0xffff0000u), ahi[2]);
        alo[3] = fmaf(v7, __uint_as_float(u7 << 16), alo[3]);
        ahi[3] = fmaf(v7, __uint_as_float(u7 & 0xffff0000u), ahi[3]);
    }
    if (e + 3 < end) {
        uint32_t c0 = csr[e], c1 = csr[e + 1], c2 = csr[e + 2], c3 = csr[e + 3];
        uint32_t u0 = xb[(size_t)(c0 & 0xffffu) * 64];
        uint32_t u1 = xb[(size_t)(c1 & 0xffffu) * 64];
        uint32_t u2 = xb[(size_t)(c2 & 0xffffu) * 64];
        uint32_t u3 = xb[(size_t)(c3 & 0xffffu) * 64];
        float v0 = __uint_as_float(c0 & 0xffff0000u), v1 = __uint_as_float(c1 & 0xffff0000u);
        float v2 = __uint_as_float(c2 & 0xffff0000u), v3 = __uint_as_float(c3 & 0xffff0000u);
        alo[0] = fmaf(v0, __uint_as_float(u0 << 16), alo[0]);
        ahi[0] = fmaf(v0, __uint_as_float(u0 & 0xffff0000u), ahi[0]);
        alo[1] = fmaf(v1, __uint_as_float(u1 << 16), alo[1]);
        ahi[1] = fmaf(v1, __uint_as_float(u1 & 0xffff0000u), ahi[1]);
        alo[2] = fmaf(v2, __uint_as_float(u2 << 16), alo[2]);
        ahi[2] = fmaf(v2, __uint_as_float(u2 & 0xffff0000u), ahi[2]);
        alo[3] = fmaf(v3, __uint_as_float(u3 << 16), alo[3]);
        ahi[3] = fmaf(v3, __uint_as_float(u3 & 0xffff0000u), ahi[3]);
        e += 4;
    }
    for (; e < end; ++e) {
        uint32_t c0 = csr[e];
        float v0 = __uint_as_float(c0 & 0xffff0000u);
        uint32_t u0 = xb[(size_t)(c0 & 0xffffu) * 64];
        alo[0] = fmaf(v0, __uint_as_float(u0 << 16), alo[0]);
        ahi[0] = fmaf(v0, __uint_as_float(u0 & 0xffff0000u), ahi[0]);
    }
    float rlo = (alo[0] + alo[1]) + (alo[2] + alo[3]);
    float rhi = (ahi[0] + ahi[1]) + (ahi[2] + ahi[3]);
    if (RELU) { rlo = fmaxf(rlo, 0.f); rhi = fmaxf(rhi, 0.f); }
    outp[(size_t)r * 64 + lane] = pack_bf16x2(rlo, rhi);
}

// D=64: xp is [N][32] packed bf16x2; half-wave per edge, 4-deep unroll per half
__global__ __launch_bounds__(256) void spmm_bf16_64(const int* __restrict__ row_ptr,
                                                    const uint32_t* __restrict__ csr,
                                                    const uint32_t* __restrict__ xp,
                                                    float* __restrict__ out) {
    const int wid = threadIdx.x >> 6;
    const int lane = threadIdx.x & 63;
    const int r = blockIdx.x * 4 + wid;
    if (r >= N_NODES) return;
    const int start = row_ptr[r];
    const int end   = row_ptr[r + 1];
    const int j = lane & 31;
    const int half = lane >> 5;
    const uint32_t* xb = xp + j;

    float alo[4] = {0.f, 0.f, 0.f, 0.f};
    float ahi[4] = {0.f, 0.f, 0.f, 0.f};
    int e = start + half;
    for (; e + 6 < end; e += 8) {
        uint32_t c0 = csr[e], c1 = csr[e + 2], c2 = csr[e + 4], c3 = csr[e + 6];
        uint32_t u0 = xb[(size_t)(c0 & 0xffffu) * 32];
        uint32_t u1 = xb[(size_t)(c1 & 0xffffu) * 32];
        uint32_t u2 = xb[(size_t)(c2 & 0xffffu) * 32];
        uint32_t u3 = xb[(size_t)(c3 & 0xffffu) * 32];
        float v0 = __uint_as_float(c0 & 0xffff0000u), v1 = __uint_as_float(c1 & 0xffff0000u);
        float v2 = __uint_as_float(c2 & 0xffff0000u), v3 = __uint_as_float(c3 & 0xffff0000u);
        alo[0] = fmaf(v0, __uint_as_float(u0 << 16), alo[0]);
        ahi[0] = fmaf(v0, __uint_as_float(u0 & 0xffff0000u), ahi[0]);
        alo[1] = fmaf(v1, __uint_as_float(u1 << 16), alo[1]);
        ahi[1] = fmaf(v1, __uint_as_float(u1 & 0xffff0000u), ahi[1]);
        alo[2] = fmaf(v2, __uint_as_float(u2 << 16), alo[2]);
        ahi[2] = fmaf(v2, __uint_as_float(u2 & 0xffff0000u), ahi[2]);
        alo[3] = fmaf(v3, __uint_as_float(u3 << 16), alo[3]);
        ahi[3] = fmaf(v3, __uint_as_float(u3 & 0xffff0000u), ahi[3]);
    }
    for (; e < end; e += 2) {
        uint32_t c0 = csr[e];
        float v = __uint_as_float(c0 & 0xffff0000u);
        uint32_t u = xb[(size_t)(c0 & 0xffffu) * 32];
        alo[0] = fmaf(v, __uint_as_float(u << 16), alo[0]);
        ahi[0] = fmaf(v, __uint_as_float(u & 0xffff0000u), ahi[0]);
    }
    float alo_s = (alo[0] + alo[1]) + (alo[2] + alo[3]);
    float ahi_s = (ahi[0] + ahi[1]) + (ahi[2] + ahi[3]);
    alo_s += __shfl_xor(alo_s, 32);
    ahi_s += __shfl_xor(ahi_s, 32);
    if (half == 0) {
        float2 res = {alo_s, ahi_s};
        *reinterpret_cast<float2*>(out + (size_t)r * 64 + j * 2) = res;
    }
}

// ---------------- launch ----------------

extern "C" void kernel_launch(void* const* d_in, const int* in_sizes, int n_in,
                              void* d_out, int out_size, void* d_ws, size_t ws_size,
                              hipStream_t stream) {
    const float* x    = (const float*)d_in[0];
    const int*   row  = (const int*)  d_in[1];
    const int*   col  = (const int*)  d_in[2];
    const float* vals = (const float*)d_in[3];
    const float* W1   = (const float*)d_in[4];
    const float* W2   = (const float*)d_in[5];
    float* out = (float*)d_out;

    // workspace layout (256B-aligned chunks); counts and gcnt contiguous so one
    // zero_ints call covers both
    char* ws = (char*)d_ws;
    auto align = [](size_t v) { return (v + 255) & ~(size_t)255; };
    int*      counts  = (int*)ws;              ws += align(sizeof(int) * (N_NODES + NBUCKETS));
    int*      gcnt    = counts + N_NODES;
    int*      row_ptr = (int*)ws;              ws += align(sizeof(int) * (N_NODES + 1));
    int*      cursor  = (int*)ws;              ws += align(sizeof(int) * N_NODES);
    int*      bsum    = (int*)ws;              ws += align(sizeof(int) * SCAN_BLOCKS);
    unsigned long long* ebuf = (unsigned long long*)ws;
                                               ws += align(sizeof(unsigned long long) * NBUCKETS * BKT_CAP);
    uint32_t* csr     = (uint32_t*)ws;         ws += align(sizeof(uint32_t) * N_EDGES);
    uint32_t* tpk     = (uint32_t*)ws;         ws += align(sizeof(uint32_t) * N_NODES * 64);
    uint32_t* hpk     = (uint32_t*)ws;         ws += align(sizeof(uint32_t) * N_NODES * 64);
    unsigned short* wt1 = (unsigned short*)ws; ws += align(sizeof(short) * 128 * 128);
    unsigned short* wt2 = (unsigned short*)ws; ws += align(sizeof(short) * 64 * 128);

    // ---- CSR build ----
    zero_ints<<<196, 256, 0, stream>>>(counts, N_NODES + NBUCKETS);
    bin_edges<<<BIN_BLOCKS, 256, 0, stream>>>(row, col, vals, counts, gcnt, ebuf);
    scan_part<<<SCAN_BLOCKS, SCAN_THREADS, 0, stream>>>(counts, bsum);
    scan_final<<<SCAN_BLOCKS, SCAN_THREADS, 0, stream>>>(counts, bsum, row_ptr, cursor);
    bucket_scatter<<<BIN_BLOCKS, 256, 0, stream>>>(gcnt, ebuf, cursor, csr);

    // ---- weights -> bf16 transposed ----
    convert_w_both<<<(128 * 128 + 64 * 128 + 255) / 256, 256, 0, stream>>>(W1, W2, wt1, wt2);

    // ---- layer 1: t1 = bf16(x @ W1); h = bf16(relu(A @ t1)) ----
    gemm_mfma<HID_DIM, true><<<dim3(196, 2), 256, 0, stream>>>(x, nullptr, wt1, (unsigned short*)tpk);
    spmm_bf16_128<true><<<(N_NODES + 3) / 4, 256, 0, stream>>>(row_ptr, csr, tpk, hpk);

    // ---- layer 2: t2 = bf16(h @ W2); out = A @ t2 ----
    gemm_mfma<OUT_DIM, false><<<dim3(196, 1), 256, 0, stream>>>(nullptr, hpk, wt2, (unsigned short*)tpk);
    spmm_bf16_64<<<(N_NODES + 3) / 4, 256, 0, stream>>>(row_ptr, csr, tpk, out);
}

// Round 13
// 172.815 us; speedup vs baseline: 3.6250x; 1.0102x over previous
//
#include <hip/hip_runtime.h>
#include <stdint.h>

#define N_NODES 50000
#define N_EDGES 800000
#define IN_DIM 128
#define HID_DIM 128
#define OUT_DIM 64

#define SCAN_BLOCKS 64
#define SCAN_THREADS 256
#define SCAN_CH 4        // 64*256*4 = 65536 >= N_NODES

#define XCD_GROUPS 8
#define ROWS_PER_XCD (N_NODES / XCD_GROUPS)   // 6250 exactly
#define SCAT_BLOCKS_PER_XCD 128

typedef short bf16x8 __attribute__((ext_vector_type(8)));
typedef float f32x4  __attribute__((ext_vector_type(4)));

__device__ __forceinline__ uint32_t pack_bf16x2(float a, float b) {
    uint32_t ba = __float_as_uint(a), bb = __float_as_uint(b);
    ba = (ba + 0x7fffu + ((ba >> 16) & 1u)) >> 16;           // RNE low half
    bb = (bb + 0x7fffu + ((bb >> 16) & 1u)) & 0xffff0000u;   // RNE high half
    return ba | bb;
}

__device__ __forceinline__ unsigned short f2bf(float f) {
    uint32_t u = __float_as_uint(f);
    return (unsigned short)((u + 0x7fffu + ((u >> 16) & 1u)) >> 16);
}

// CSR entry: high 16 bits = bf16(val), low 16 bits = col (col < 65536)
__device__ __forceinline__ uint32_t pack_edge(int col, float v) {
    uint32_t fb = __float_as_uint(v);
    fb = (fb + 0x7fffu + ((fb >> 16) & 1u)) & 0xffff0000u;
    return fb | (uint32_t)col;
}

// ---------------- CSR build ----------------

__global__ void zero_ints(int* __restrict__ p, int n) {
    int i = blockIdx.x * blockDim.x + threadIdx.x;
    int stride = gridDim.x * blockDim.x;
    for (; i < n; i += stride) p[i] = 0;
}

__global__ void hist_rows(const int* __restrict__ row, int* __restrict__ counts) {
    int e = blockIdx.x * blockDim.x + threadIdx.x;
    int stride = gridDim.x * blockDim.x;
    for (; e < N_EDGES; e += stride) atomicAdd(&counts[row[e]], 1);
}

__global__ __launch_bounds__(SCAN_THREADS) void scan_part(const int* __restrict__ counts,
                                                          int* __restrict__ bsum) {
    __shared__ int red[SCAN_THREADS];
    const int b = blockIdx.x, t = threadIdx.x;
    const int base = (b * SCAN_THREADS + t) * SCAN_CH;
    int s = 0;
#pragma unroll
    for (int i = 0; i < SCAN_CH; ++i) {
        int idx = base + i;
        if (idx < N_NODES) s += counts[idx];
    }
    red[t] = s;
    __syncthreads();
#pragma unroll
    for (int off = SCAN_THREADS / 2; off > 0; off >>= 1) {
        if (t < off) red[t] += red[t + off];
        __syncthreads();
    }
    if (t == 0) bsum[b] = red[0];
}

__global__ __launch_bounds__(SCAN_THREADS) void scan_final(const int* __restrict__ counts,
                                                           const int* __restrict__ bsum,
                                                           int* __restrict__ row_ptr,
                                                           int* __restrict__ cursor) {
    __shared__ int sums[SCAN_THREADS];
    __shared__ int sh_boff;
    const int b = blockIdx.x, t = threadIdx.x;
    if (t == 0) {
        int s = 0;
        for (int i = 0; i < b; ++i) s += bsum[i];
        sh_boff = s;
    }
    const int base = (b * SCAN_THREADS + t) * SCAN_CH;
    int local[SCAN_CH];
    int s = 0;
#pragma unroll
    for (int i = 0; i < SCAN_CH; ++i) {
        int idx = base + i;
        int c = (idx < N_NODES) ? counts[idx] : 0;
        local[i] = c;
        s += c;
    }
    sums[t] = s;
    __syncthreads();
#pragma unroll
    for (int off = 1; off < SCAN_THREADS; off <<= 1) {
        int v = sums[t];
        int add = (t >= off) ? sums[t - off] : 0;
        __syncthreads();
        sums[t] = v + add;
        __syncthreads();
    }
    int run = sh_boff + sums[t] - s;
#pragma unroll
    for (int i = 0; i < SCAN_CH; ++i) {
        int idx = base + i;
        if (idx < N_NODES) {
            row_ptr[idx] = run;
            cursor[idx]  = run;
            run += local[i];
        }
    }
    if (b == 0 && t == 0) row_ptr[N_NODES] = N_EDGES;
}

// scatter edges into packed 4B CSR, XCD-partitioned destinations:
// blocks with same (blockIdx & 7) land on same XCD (round-robin dispatch);
// group g owns rows [g*6250,(g+1)*6250) -> dest region ~0.4MB is L2-local,
// lines fill completely before writeback (proven R7: removed 52MB write amp)
__global__ __launch_bounds__(256) void scatter_xcd(const int* __restrict__ row,
                                                   const int* __restrict__ col,
                                                   const float* __restrict__ vals,
                                                   int* __restrict__ cursor,
                                                   uint32_t* __restrict__ csr) {
    const int xcd = blockIdx.x & (XCD_GROUPS - 1);
    const int blk = blockIdx.x >> 3;
    const int rlo = xcd * ROWS_PER_XCD;
    int e = blk * 256 + threadIdx.x;
    const int stride = SCAT_BLOCKS_PER_XCD * 256;
    for (; e < N_EDGES; e += stride) {
        int r = row[e];
        if ((unsigned)(r - rlo) < (unsigned)ROWS_PER_XCD) {
            int p = atomicAdd(&cursor[r], 1);
            csr[p] = pack_edge(col[e], vals[e]);
        }
    }
}

// ---------------- weights -> bf16 transposed ----------------

__global__ void convert_w_both(const float* __restrict__ W1, const float* __restrict__ W2,
                               unsigned short* __restrict__ wt1, unsigned short* __restrict__ wt2) {
    int i = blockIdx.x * blockDim.x + threadIdx.x;
    if (i < 128 * 128) {
        int n = i >> 7, k = i & 127;
        wt1[i] = f2bf(W1[k * 128 + n]);
    } else if (i < 128 * 128 + 64 * 128) {
        int j = i - 128 * 128;
        int n = j >> 7, k = j & 127;
        wt2[j] = f2bf(W2[k * 64 + n]);
    }
}

// ---------------- MFMA GEMM: outb[M,N](bf16) = A[M,128] @ W[128,N] ----------------
// 16x16x32 bf16 MFMA layouts (HW-verified):
//   A: row=lane&15, k=(lane>>4)*8+j ; B from Wt[n][k]: col=lane&15, same k
//   D: col=lane&15, row=(lane>>4)*4+reg.  50000 rows = 3125 m-tiles exactly.

template<int N, bool AF32>
__global__ __launch_bounds__(256) void gemm_mfma(const float* __restrict__ Af,
                                                 const uint32_t* __restrict__ Apk,
                                                 const unsigned short* __restrict__ Wt,
                                                 unsigned short* __restrict__ outb) {
    const int tid = threadIdx.x;
    const int wid = tid >> 6, lane = tid & 63;
    const int l15 = lane & 15, lk = lane >> 4;
    const int n0 = blockIdx.y * 64;

    bf16x8 bfrag[4][4];
#pragma unroll
    for (int t = 0; t < 4; ++t) {
        const unsigned short* wp = Wt + (size_t)(n0 + t * 16 + l15) * 128 + lk * 8;
#pragma unroll
        for (int s = 0; s < 4; ++s)
            bfrag[t][s] = *reinterpret_cast<const bf16x8*>(wp + s * 32);
    }

    for (int mt = blockIdx.x * 4 + wid; mt < 3125; mt += 784) {
        const int row = mt * 16 + l15;
        bf16x8 afrag[4];
        if (AF32) {
            const float* ap = Af + (size_t)row * 128 + lk * 8;
#pragma unroll
            for (int s = 0; s < 4; ++s) {
                float4 p0 = *reinterpret_cast<const float4*>(ap + s * 32);
                float4 p1 = *reinterpret_cast<const float4*>(ap + s * 32 + 4);
                bf16x8 f;
                f[0] = (short)f2bf(p0.x); f[1] = (short)f2bf(p0.y);
                f[2] = (short)f2bf(p0.z); f[3] = (short)f2bf(p0.w);
                f[4] = (short)f2bf(p1.x); f[5] = (short)f2bf(p1.y);
                f[6] = (short)f2bf(p1.z); f[7] = (short)f2bf(p1.w);
                afrag[s] = f;
            }
        } else {
            const uint32_t* ap = Apk + (size_t)row * 64 + lk * 4;
#pragma unroll
            for (int s = 0; s < 4; ++s)
                afrag[s] = *reinterpret_cast<const bf16x8*>(ap + s * 16);
        }

        f32x4 acc[4] = {{0.f,0.f,0.f,0.f},{0.f,0.f,0.f,0.f},{0.f,0.f,0.f,0.f},{0.f,0.f,0.f,0.f}};
#pragma unroll
        for (int s = 0; s < 4; ++s)
#pragma unroll
            for (int t = 0; t < 4; ++t)
                acc[t] = __builtin_amdgcn_mfma_f32_16x16x32_bf16(afrag[s], bfrag[t][s], acc[t], 0, 0, 0);

#pragma unroll
        for (int t = 0; t < 4; ++t)
#pragma unroll
            for (int q = 0; q < 4; ++q) {
                int r = mt * 16 + lk * 4 + q;
                outb[(size_t)r * N + n0 + t * 16 + l15] = f2bf(acc[t][q]);
            }
    }
}

// ---------------- CSR SPMM over bf16-packed operand, f32 accumulate ----------------

// D=128: xp is [N][64] packed bf16x2; lane = dims {2l,2l+1}; 8-deep + 4-deep tail.
template<bool RELU>
__global__ __launch_bounds__(256) void spmm_bf16_128(const int* __restrict__ row_ptr,
                                                     const uint32_t* __restrict__ csr,
                                                     const uint32_t* __restrict__ xp,
                                                     uint32_t* __restrict__ outp) {
    const int wid = threadIdx.x >> 6;
    const int lane = threadIdx.x & 63;
    const int r = blockIdx.x * 4 + wid;
    if (r >= N_NODES) return;
    const int start = row_ptr[r];
    const int end   = row_ptr[r + 1];
    const uint32_t* xb = xp + lane;

    float alo[4] = {0.f, 0.f, 0.f, 0.f};
    float ahi[4] = {0.f, 0.f, 0.f, 0.f};
    int e = start;
    for (; e + 7 < end; e += 8) {
        uint32_t c0 = csr[e],     c1 = csr[e + 1], c2 = csr[e + 2], c3 = csr[e + 3];
        uint32_t c4 = csr[e + 4], c5 = csr[e + 5], c6 = csr[e + 6], c7 = csr[e + 7];
        uint32_t u0 = xb[(size_t)(c0 & 0xffffu) * 64];
        uint32_t u1 = xb[(size_t)(c1 & 0xffffu) * 64];
        uint32_t u2 = xb[(size_t)(c2 & 0xffffu) * 64];
        uint32_t u3 = xb[(size_t)(c3 & 0xffffu) * 64];
        uint32_t u4 = xb[(size_t)(c4 & 0xffffu) * 64];
        uint32_t u5 = xb[(size_t)(c5 & 0xffffu) * 64];
        uint32_t u6 = xb[(size_t)(c6 & 0xffffu) * 64];
        uint32_t u7 = xb[(size_t)(c7 & 0xffffu) * 64];
        float v0 = __uint_as_float(c0 & 0xffff0000u), v1 = __uint_as_float(c1 & 0xffff0000u);
        float v2 = __uint_as_float(c2 & 0xffff0000u), v3 = __uint_as_float(c3 & 0xffff0000u);
        float v4 = __uint_as_float(c4 & 0xffff0000u), v5 = __uint_as_float(c5 & 0xffff0000u);
        float v6 = __uint_as_float(c6 & 0xffff0000u), v7 = __uint_as_float(c7 & 0xffff0000u);
        alo[0] = fmaf(v0, __uint_as_float(u0 << 16), alo[0]);
        ahi[0] = fmaf(v0, __uint_as_float(u0 & 0xffff0000u), ahi[0]);
        alo[1] = fmaf(v1, __uint_as_float(u1 << 16), alo[1]);
        ahi[1] = fmaf(v1, __uint_as_float(u1 & 0xffff0000u), ahi[1]);
        alo[2] = fmaf(v2, __uint_as_float(u2 << 16), alo[2]);
        ahi[2] = fmaf(v2, __uint_as_float(u2 & 0xffff0000u), ahi[2]);
        alo[3] = fmaf(v3, __uint_as_float(u3 << 16), alo[3]);
        ahi[3] = fmaf(v3, __uint_as_float(u3 & 0xffff0000u), ahi[3]);
        alo[0] = fmaf(v4, __uint_as_float(u4 << 16), alo[0]);
        ahi[0] = fmaf(v4, __uint_as_float(u4 & 0xffff0000u), ahi[0]);
        alo[1] = fmaf(v5, __uint_as_float(u5 << 16), alo[1]);
        ahi[1] = fmaf(v5, __uint_as_float(u5 & 0xffff0000u), ahi[1]);
        alo[2] = fmaf(v6, __uint_as_float(u6 << 16), alo[2]);
        ahi[2] = fmaf(v6, __uint_as_float(u6 & 0xffff0000u), ahi[2]);
        alo[3] = fmaf(v7, __uint_as_float(u7 << 16), alo[3]);
        ahi[3] = fmaf(v7, __uint_as_float(u7 & 0xffff0000u), ahi[3]);
    }
    if (e + 3 < end) {
        uint32_t c0 = csr[e], c1 = csr[e + 1], c2 = csr[e + 2], c3 = csr[e + 3];
        uint32_t u0 = xb[(size_t)(c0 & 0xffffu) * 64];
        uint32_t u1 = xb[(size_t)(c1 & 0xffffu) * 64];
        uint32_t u2 = xb[(size_t)(c2 & 0xffffu) * 64];
        uint32_t u3 = xb[(size_t)(c3 & 0xffffu) * 64];
        float v0 = __uint_as_float(c0 & 0xffff0000u), v1 = __uint_as_float(c1 & 0xffff0000u);
        float v2 = __uint_as_float(c2 & 0xffff0000u), v3 = __uint_as_float(c3 & 0xffff0000u);
        alo[0] = fmaf(v0, __uint_as_float(u0 << 16), alo[0]);
        ahi[0] = fmaf(v0, __uint_as_float(u0 & 0xffff0000u), ahi[0]);
        alo[1] = fmaf(v1, __uint_as_float(u1 << 16), alo[1]);
        ahi[1] = fmaf(v1, __uint_as_float(u1 & 0xffff0000u), ahi[1]);
        alo[2] = fmaf(v2, __uint_as_float(u2 << 16), alo[2]);
        ahi[2] = fmaf(v2, __uint_as_float(u2 & 0xffff0000u), ahi[2]);
        alo[3] = fmaf(v3, __uint_as_float(u3 << 16), alo[3]);
        ahi[3] = fmaf(v3, __uint_as_float(u3 & 0xffff0000u), ahi[3]);
        e += 4;
    }
    for (; e < end; ++e) {
        uint32_t c0 = csr[e];
        float v0 = __uint_as_float(c0 & 0xffff0000u);
        uint32_t u0 = xb[(size_t)(c0 & 0xffffu) * 64];
        alo[0] = fmaf(v0, __uint_as_float(u0 << 16), alo[0]);
        ahi[0] = fmaf(v0, __uint_as_float(u0 & 0xffff0000u), ahi[0]);
    }
    float rlo = (alo[0] + alo[1]) + (alo[2] + alo[3]);
    float rhi = (ahi[0] + ahi[1]) + (ahi[2] + ahi[3]);
    if (RELU) { rlo = fmaxf(rlo, 0.f); rhi = fmaxf(rhi, 0.f); }
    outp[(size_t)r * 64 + lane] = pack_bf16x2(rlo, rhi);
}

// D=64: xp is [N][32] packed bf16x2; half-wave per edge, 4-deep unroll per half
__global__ __launch_bounds__(256) void spmm_bf16_64(const int* __restrict__ row_ptr,
                                                    const uint32_t* __restrict__ csr,
                                                    const uint32_t* __restrict__ xp,
                                                    float* __restrict__ out) {
    const int wid = threadIdx.x >> 6;
    const int lane = threadIdx.x & 63;
    const int r = blockIdx.x * 4 + wid;
    if (r >= N_NODES) return;
    const int start = row_ptr[r];
    const int end   = row_ptr[r + 1];
    const int j = lane & 31;
    const int half = lane >> 5;
    const uint32_t* xb = xp + j;

    float alo[4] = {0.f, 0.f, 0.f, 0.f};
    float ahi[4] = {0.f, 0.f, 0.f, 0.f};
    int e = start + half;
    for (; e + 6 < end; e += 8) {
        uint32_t c0 = csr[e], c1 = csr[e + 2], c2 = csr[e + 4], c3 = csr[e + 6];
        uint32_t u0 = xb[(size_t)(c0 & 0xffffu) * 32];
        uint32_t u1 = xb[(size_t)(c1 & 0xffffu) * 32];
        uint32_t u2 = xb[(size_t)(c2 & 0xffffu) * 32];
        uint32_t u3 = xb[(size_t)(c3 & 0xffffu) * 32];
        float v0 = __uint_as_float(c0 & 0xffff0000u), v1 = __uint_as_float(c1 & 0xffff0000u);
        float v2 = __uint_as_float(c2 & 0xffff0000u), v3 = __uint_as_float(c3 & 0xffff0000u);
        alo[0] = fmaf(v0, __uint_as_float(u0 << 16), alo[0]);
        ahi[0] = fmaf(v0, __uint_as_float(u0 & 0xffff0000u), ahi[0]);
        alo[1] = fmaf(v1, __uint_as_float(u1 << 16), alo[1]);
        ahi[1] = fmaf(v1, __uint_as_float(u1 & 0xffff0000u), ahi[1]);
        alo[2] = fmaf(v2, __uint_as_float(u2 << 16), alo[2]);
        ahi[2] = fmaf(v2, __uint_as_float(u2 & 0xffff0000u), ahi[2]);
        alo[3] = fmaf(v3, __uint_as_float(u3 << 16), alo[3]);
        ahi[3] = fmaf(v3, __uint_as_float(u3 & 0xffff0000u), ahi[3]);
    }
    for (; e < end; e += 2) {
        uint32_t c0 = csr[e];
        float v = __uint_as_float(c0 & 0xffff0000u);
        uint32_t u = xb[(size_t)(c0 & 0xffffu) * 32];
        alo[0] = fmaf(v, __uint_as_float(u << 16), alo[0]);
        ahi[0] = fmaf(v, __uint_as_float(u & 0xffff0000u), ahi[0]);
    }
    float alo_s = (alo[0] + alo[1]) + (alo[2] + alo[3]);
    float ahi_s = (ahi[0] + ahi[1]) + (ahi[2] + ahi[3]);
    alo_s += __shfl_xor(alo_s, 32);
    ahi_s += __shfl_xor(ahi_s, 32);
    if (half == 0) {
        float2 res = {alo_s, ahi_s};
        *reinterpret_cast<float2*>(out + (size_t)r * 64 + j * 2) = res;
    }
}

// ---------------- launch ----------------

extern "C" void kernel_launch(void* const* d_in, const int* in_sizes, int n_in,
                              void* d_out, int out_size, void* d_ws, size_t ws_size,
                              hipStream_t stream) {
    const float* x    = (const float*)d_in[0];
    const int*   row  = (const int*)  d_in[1];
    const int*   col  = (const int*)  d_in[2];
    const float* vals = (const float*)d_in[3];
    const float* W1   = (const float*)d_in[4];
    const float* W2   = (const float*)d_in[5];
    float* out = (float*)d_out;

    // workspace layout (256B-aligned chunks)
    char* ws = (char*)d_ws;
    auto align = [](size_t v) { return (v + 255) & ~(size_t)255; };
    int*      counts  = (int*)ws;              ws += align(sizeof(int) * N_NODES);
    int*      row_ptr = (int*)ws;              ws += align(sizeof(int) * (N_NODES + 1));
    int*      cursor  = (int*)ws;              ws += align(sizeof(int) * N_NODES);
    int*      bsum    = (int*)ws;              ws += align(sizeof(int) * SCAN_BLOCKS);
    uint32_t* csr     = (uint32_t*)ws;         ws += align(sizeof(uint32_t) * N_EDGES);
    uint32_t* tpk     = (uint32_t*)ws;         ws += align(sizeof(uint32_t) * N_NODES * 64);
    uint32_t* hpk     = (uint32_t*)ws;         ws += align(sizeof(uint32_t) * N_NODES * 64);
    unsigned short* wt1 = (unsigned short*)ws; ws += align(sizeof(short) * 128 * 128);
    unsigned short* wt2 = (unsigned short*)ws; ws += align(sizeof(short) * 64 * 128);

    // ---- CSR build ----
    zero_ints<<<196, 256, 0, stream>>>(counts, N_NODES);
    hist_rows<<<1024, 256, 0, stream>>>(row, counts);
    scan_part<<<SCAN_BLOCKS, SCAN_THREADS, 0, stream>>>(counts, bsum);
    scan_final<<<SCAN_BLOCKS, SCAN_THREADS, 0, stream>>>(counts, bsum, row_ptr, cursor);
    scatter_xcd<<<SCAT_BLOCKS_PER_XCD * XCD_GROUPS, 256, 0, stream>>>(row, col, vals, cursor, csr);

    // ---- weights -> bf16 transposed ----
    convert_w_both<<<(128 * 128 + 64 * 128 + 255) / 256, 256, 0, stream>>>(W1, W2, wt1, wt2);

    // ---- layer 1: t1 = bf16(x @ W1); h = bf16(relu(A @ t1)) ----
    gemm_mfma<HID_DIM, true><<<dim3(196, 2), 256, 0, stream>>>(x, nullptr, wt1, (unsigned short*)tpk);
    spmm_bf16_128<true><<<(N_NODES + 3) / 4, 256, 0, stream>>>(row_ptr, csr, tpk, hpk);

    // ---- layer 2: t2 = bf16(h @ W2); out = A @ t2 ----
    gemm_mfma<OUT_DIM, false><<<dim3(196, 1), 256, 0, stream>>>(nullptr, hpk, wt2, (unsigned short*)tpk);
    spmm_bf16_64<<<(N_NODES + 3) / 4, 256, 0, stream>>>(row_ptr, csr, tpk, out);
}

// Round 14
// 130.645 us; speedup vs baseline: 4.7951x; 1.3228x over previous
//
#include <hip/hip_runtime.h>
#include <stdint.h>

#define N_NODES 50000
#define N_EDGES 800000
#define IN_DIM 128
#define HID_DIM 128
#define OUT_DIM 64

#define ELL_CAP 64                            // slots/row; Poisson(16) max deg ~38
#define XCD_GROUPS 8
#define ROWS_PER_XCD (N_NODES / XCD_GROUPS)   // 6250 exactly
#define SCAT_BLOCKS_PER_XCD 128

typedef short bf16x8 __attribute__((ext_vector_type(8)));
typedef float f32x4  __attribute__((ext_vector_type(4)));

__device__ __forceinline__ uint32_t pack_bf16x2(float a, float b) {
    uint32_t ba = __float_as_uint(a), bb = __float_as_uint(b);
    ba = (ba + 0x7fffu + ((ba >> 16) & 1u)) >> 16;           // RNE low half
    bb = (bb + 0x7fffu + ((bb >> 16) & 1u)) & 0xffff0000u;   // RNE high half
    return ba | bb;
}

__device__ __forceinline__ unsigned short f2bf(float f) {
    uint32_t u = __float_as_uint(f);
    return (unsigned short)((u + 0x7fffu + ((u >> 16) & 1u)) >> 16);
}

// ELL entry: high 16 bits = bf16(val), low 16 bits = col (col < 65536)
__device__ __forceinline__ uint32_t pack_edge(int col, float v) {
    uint32_t fb = __float_as_uint(v);
    fb = (fb + 0x7fffu + ((fb >> 16) & 1u)) & 0xffff0000u;
    return fb | (uint32_t)col;
}

// ---------------- fused init: zero ELL counts + convert weights to bf16^T ----------------
// wt1[n*128+k] = bf16(W1[k*128+n]);  wt2[n*128+k] = bf16(W2[k*64+n])

__global__ __launch_bounds__(256) void zero_convert(int* __restrict__ counts,
                                                    const float* __restrict__ W1,
                                                    const float* __restrict__ W2,
                                                    unsigned short* __restrict__ wt1,
                                                    unsigned short* __restrict__ wt2) {
    int i = blockIdx.x * 256 + threadIdx.x;
    if (i < N_NODES) counts[i] = 0;
    int j = i - N_NODES;
    if (j >= 0 && j < 128 * 128) {
        int n = j >> 7, k = j & 127;
        wt1[j] = f2bf(W1[k * 128 + n]);
    }
    int l = j - 128 * 128;
    if (l >= 0 && l < 64 * 128) {
        int n = l >> 7, k = l & 127;
        wt2[l] = f2bf(W2[k * 64 + n]);
    }
}

// ---------------- ELL build: single scatter pass, XCD-partitioned destinations ----------------
// blocks with same (blockIdx & 7) land on same XCD (round-robin dispatch); group g
// owns rows [g*6250,(g+1)*6250) -> dest region ~1.6MB is L2-local (proven R7).
// counts[] doubles as cursor and final row degree.

__global__ __launch_bounds__(256) void scatter_ell(const int* __restrict__ row,
                                                   const int* __restrict__ col,
                                                   const float* __restrict__ vals,
                                                   int* __restrict__ counts,
                                                   uint32_t* __restrict__ ell) {
    const int xcd = blockIdx.x & (XCD_GROUPS - 1);
    const int blk = blockIdx.x >> 3;
    const int rlo = xcd * ROWS_PER_XCD;
    int e = blk * 256 + threadIdx.x;
    const int stride = SCAT_BLOCKS_PER_XCD * 256;
    for (; e < N_EDGES; e += stride) {
        int r = row[e];
        if ((unsigned)(r - rlo) < (unsigned)ROWS_PER_XCD) {
            int p = atomicAdd(&counts[r], 1);
            if (p < ELL_CAP)   // unreachable for Poisson(16); memory-safety guard
                ell[((size_t)r << 6) + p] = pack_edge(col[e], vals[e]);
        }
    }
}

// ---------------- MFMA GEMM: outb[M,N](bf16) = A[M,128] @ W[128,N] ----------------
// 16x16x32 bf16 MFMA layouts (HW-verified):
//   A: row=lane&15, k=(lane>>4)*8+j ; B from Wt[n][k]: col=lane&15, same k
//   D: col=lane&15, row=(lane>>4)*4+reg.  50000 rows = 3125 m-tiles exactly.

template<int N, bool AF32>
__global__ __launch_bounds__(256) void gemm_mfma(const float* __restrict__ Af,
                                                 const uint32_t* __restrict__ Apk,
                                                 const unsigned short* __restrict__ Wt,
                                                 unsigned short* __restrict__ outb) {
    const int tid = threadIdx.x;
    const int wid = tid >> 6, lane = tid & 63;
    const int l15 = lane & 15, lk = lane >> 4;
    const int n0 = blockIdx.y * 64;

    bf16x8 bfrag[4][4];
#pragma unroll
    for (int t = 0; t < 4; ++t) {
        const unsigned short* wp = Wt + (size_t)(n0 + t * 16 + l15) * 128 + lk * 8;
#pragma unroll
        for (int s = 0; s < 4; ++s)
            bfrag[t][s] = *reinterpret_cast<const bf16x8*>(wp + s * 32);
    }

    for (int mt = blockIdx.x * 4 + wid; mt < 3125; mt += 784) {
        const int row = mt * 16 + l15;
        bf16x8 afrag[4];
        if (AF32) {
            const float* ap = Af + (size_t)row * 128 + lk * 8;
#pragma unroll
            for (int s = 0; s < 4; ++s) {
                float4 p0 = *reinterpret_cast<const float4*>(ap + s * 32);
                float4 p1 = *reinterpret_cast<const float4*>(ap + s * 32 + 4);
                bf16x8 f;
                f[0] = (short)f2bf(p0.x); f[1] = (short)f2bf(p0.y);
                f[2] = (short)f2bf(p0.z); f[3] = (short)f2bf(p0.w);
                f[4] = (short)f2bf(p1.x); f[5] = (short)f2bf(p1.y);
                f[6] = (short)f2bf(p1.z); f[7] = (short)f2bf(p1.w);
                afrag[s] = f;
            }
        } else {
            const uint32_t* ap = Apk + (size_t)row * 64 + lk * 4;
#pragma unroll
            for (int s = 0; s < 4; ++s)
                afrag[s] = *reinterpret_cast<const bf16x8*>(ap + s * 16);
        }

        f32x4 acc[4] = {{0.f,0.f,0.f,0.f},{0.f,0.f,0.f,0.f},{0.f,0.f,0.f,0.f},{0.f,0.f,0.f,0.f}};
#pragma unroll
        for (int s = 0; s < 4; ++s)
#pragma unroll
            for (int t = 0; t < 4; ++t)
                acc[t] = __builtin_amdgcn_mfma_f32_16x16x32_bf16(afrag[s], bfrag[t][s], acc[t], 0, 0, 0);

#pragma unroll
        for (int t = 0; t < 4; ++t)
#pragma unroll
            for (int q = 0; q < 4; ++q) {
                int r = mt * 16 + lk * 4 + q;
                outb[(size_t)r * N + n0 + t * 16 + l15] = f2bf(acc[t][q]);
            }
    }
}

// ---------------- ELL SPMM over bf16-packed operand, f32 accumulate ----------------

// D=128: xp is [N][64] packed bf16x2; lane = dims {2l,2l+1}; 8-deep + 4-deep tail.
template<bool RELU>
__global__ __launch_bounds__(256) void spmm_bf16_128(const int* __restrict__ counts,
                                                     const uint32_t* __restrict__ ell,
                                                     const uint32_t* __restrict__ xp,
                                                     uint32_t* __restrict__ outp) {
    const int wid = threadIdx.x >> 6;
    const int lane = threadIdx.x & 63;
    const int r = blockIdx.x * 4 + wid;
    if (r >= N_NODES) return;
    const int start = r << 6;
    int cnt = counts[r]; if (cnt > ELL_CAP) cnt = ELL_CAP;
    const int end = start + cnt;
    const uint32_t* xb = xp + lane;

    float alo[4] = {0.f, 0.f, 0.f, 0.f};
    float ahi[4] = {0.f, 0.f, 0.f, 0.f};
    int e = start;
    for (; e + 7 < end; e += 8) {
        uint32_t c0 = ell[e],     c1 = ell[e + 1], c2 = ell[e + 2], c3 = ell[e + 3];
        uint32_t c4 = ell[e + 4], c5 = ell[e + 5], c6 = ell[e + 6], c7 = ell[e + 7];
        uint32_t u0 = xb[(size_t)(c0 & 0xffffu) * 64];
        uint32_t u1 = xb[(size_t)(c1 & 0xffffu) * 64];
        uint32_t u2 = xb[(size_t)(c2 & 0xffffu) * 64];
        uint32_t u3 = xb[(size_t)(c3 & 0xffffu) * 64];
        uint32_t u4 = xb[(size_t)(c4 & 0xffffu) * 64];
        uint32_t u5 = xb[(size_t)(c5 & 0xffffu) * 64];
        uint32_t u6 = xb[(size_t)(c6 & 0xffffu) * 64];
        uint32_t u7 = xb[(size_t)(c7 & 0xffffu) * 64];
        float v0 = __uint_as_float(c0 & 0xffff0000u), v1 = __uint_as_float(c1 & 0xffff0000u);
        float v2 = __uint_as_float(c2 & 0xffff0000u), v3 = __uint_as_float(c3 & 0xffff0000u);
        float v4 = __uint_as_float(c4 & 0xffff0000u), v5 = __uint_as_float(c5 & 0xffff0000u);
        float v6 = __uint_as_float(c6 & 0xffff0000u), v7 = __uint_as_float(c7 & 0xffff0000u);
        alo[0] = fmaf(v0, __uint_as_float(u0 << 16), alo[0]);
        ahi[0] = fmaf(v0, __uint_as_float(u0 & 0xffff0000u), ahi[0]);
        alo[1] = fmaf(v1, __uint_as_float(u1 << 16), alo[1]);
        ahi[1] = fmaf(v1, __uint_as_float(u1 & 0xffff0000u), ahi[1]);
        alo[2] = fmaf(v2, __uint_as_float(u2 << 16), alo[2]);
        ahi[2] = fmaf(v2, __uint_as_float(u2 & 0xffff0000u), ahi[2]);
        alo[3] = fmaf(v3, __uint_as_float(u3 << 16), alo[3]);
        ahi[3] = fmaf(v3, __uint_as_float(u3 & 0xffff0000u), ahi[3]);
        alo[0] = fmaf(v4, __uint_as_float(u4 << 16), alo[0]);
        ahi[0] = fmaf(v4, __uint_as_float(u4 & 0xffff0000u), ahi[0]);
        alo[1] = fmaf(v5, __uint_as_float(u5 << 16), alo[1]);
        ahi[1] = fmaf(v5, __uint_as_float(u5 & 0xffff0000u), ahi[1]);
        alo[2] = fmaf(v6, __uint_as_float(u6 << 16), alo[2]);
        ahi[2] = fmaf(v6, __uint_as_float(u6 & 0xffff0000u), ahi[2]);
        alo[3] = fmaf(v7, __uint_as_float(u7 << 16), alo[3]);
        ahi[3] = fmaf(v7, __uint_as_float(u7 & 0xffff0000u), ahi[3]);
    }
    if (e + 3 < end) {
        uint32_t c0 = ell[e], c1 = ell[e + 1], c2 = ell[e + 2], c3 = ell[e + 3];
        uint32_t u0 = xb[(size_t)(c0 & 0xffffu) * 64];
        uint32_t u1 = xb[(size_t)(c1 & 0xffffu) * 64];
        uint32_t u2 = xb[(size_t)(c2 & 0xffffu) * 64];
        uint32_t u3 = xb[(size_t)(c3 & 0xffffu) * 64];
        float v0 = __uint_as_float(c0 & 0xffff0000u), v1 = __uint_as_float(c1 & 0xffff0000u);
        float v2 = __uint_as_float(c2 & 0xffff0000u), v3 = __uint_as_float(c3 & 0xffff0000u);
        alo[0] = fmaf(v0, __uint_as_float(u0 << 16), alo[0]);
        ahi[0] = fmaf(v0, __uint_as_float(u0 & 0xffff0000u), ahi[0]);
        alo[1] = fmaf(v1, __uint_as_float(u1 << 16), alo[1]);
        ahi[1] = fmaf(v1, __uint_as_float(u1 & 0xffff0000u), ahi[1]);
        alo[2] = fmaf(v2, __uint_as_float(u2 << 16), alo[2]);
        ahi[2] = fmaf(v2, __uint_as_float(u2 & 0xffff0000u), ahi[2]);
        alo[3] = fmaf(v3, __uint_as_float(u3 << 16), alo[3]);
        ahi[3] = fmaf(v3, __uint_as_float(u3 & 0xffff0000u), ahi[3]);
        e += 4;
    }
    for (; e < end; ++e) {
        uint32_t c0 = ell[e];
        float v0 = __uint_as_float(c0 & 0xffff0000u);
        uint32_t u0 = xb[(size_t)(c0 & 0xffffu) * 64];
        alo[0] = fmaf(v0, __uint_as_float(u0 << 16), alo[0]);
        ahi[0] = fmaf(v0, __uint_as_float(u0 & 0xffff0000u), ahi[0]);
    }
    float rlo = (alo[0] + alo[1]) + (alo[2] + alo[3]);
    float rhi = (ahi[0] + ahi[1]) + (ahi[2] + ahi[3]);
    if (RELU) { rlo = fmaxf(rlo, 0.f); rhi = fmaxf(rhi, 0.f); }
    outp[(size_t)r * 64 + lane] = pack_bf16x2(rlo, rhi);
}

// D=64: xp is [N][32] packed bf16x2; half-wave per edge, 4-deep unroll per half
__global__ __launch_bounds__(256) void spmm_bf16_64(const int* __restrict__ counts,
                                                    const uint32_t* __restrict__ ell,
                                                    const uint32_t* __restrict__ xp,
                                                    float* __restrict__ out) {
    const int wid = threadIdx.x >> 6;
    const int lane = threadIdx.x & 63;
    const int r = blockIdx.x * 4 + wid;
    if (r >= N_NODES) return;
    const int start = r << 6;
    int cnt = counts[r]; if (cnt > ELL_CAP) cnt = ELL_CAP;
    const int end = start + cnt;
    const int j = lane & 31;
    const int half = lane >> 5;
    const uint32_t* xb = xp + j;

    float alo[4] = {0.f, 0.f, 0.f, 0.f};
    float ahi[4] = {0.f, 0.f, 0.f, 0.f};
    int e = start + half;
    for (; e + 6 < end; e += 8) {
        uint32_t c0 = ell[e], c1 = ell[e + 2], c2 = ell[e + 4], c3 = ell[e + 6];
        uint32_t u0 = xb[(size_t)(c0 & 0xffffu) * 32];
        uint32_t u1 = xb[(size_t)(c1 & 0xffffu) * 32];
        uint32_t u2 = xb[(size_t)(c2 & 0xffffu) * 32];
        uint32_t u3 = xb[(size_t)(c3 & 0xffffu) * 32];
        float v0 = __uint_as_float(c0 & 0xffff0000u), v1 = __uint_as_float(c1 & 0xffff0000u);
        float v2 = __uint_as_float(c2 & 0xffff0000u), v3 = __uint_as_float(c3 & 0xffff0000u);
        alo[0] = fmaf(v0, __uint_as_float(u0 << 16), alo[0]);
        ahi[0] = fmaf(v0, __uint_as_float(u0 & 0xffff0000u), ahi[0]);
        alo[1] = fmaf(v1, __uint_as_float(u1 << 16), alo[1]);
        ahi[1] = fmaf(v1, __uint_as_float(u1 & 0xffff0000u), ahi[1]);
        alo[2] = fmaf(v2, __uint_as_float(u2 << 16), alo[2]);
        ahi[2] = fmaf(v2, __uint_as_float(u2 & 0xffff0000u), ahi[2]);
        alo[3] = fmaf(v3, __uint_as_float(u3 << 16), alo[3]);
        ahi[3] = fmaf(v3, __uint_as_float(u3 & 0xffff0000u), ahi[3]);
    }
    for (; e < end; e += 2) {
        uint32_t c0 = ell[e];
        float v = __uint_as_float(c0 & 0xffff0000u);
        uint32_t u = xb[(size_t)(c0 & 0xffffu) * 32];
        alo[0] = fmaf(v, __uint_as_float(u << 16), alo[0]);
        ahi[0] = fmaf(v, __uint_as_float(u & 0xffff0000u), ahi[0]);
    }
    float alo_s = (alo[0] + alo[1]) + (alo[2] + alo[3]);
    float ahi_s = (ahi[0] + ahi[1]) + (ahi[2] + ahi[3]);
    alo_s += __shfl_xor(alo_s, 32);
    ahi_s += __shfl_xor(ahi_s, 32);
    if (half == 0) {
        float2 res = {alo_s, ahi_s};
        *reinterpret_cast<float2*>(out + (size_t)r * 64 + j * 2) = res;
    }
}

// ---------------- launch (6 dispatches) ----------------

extern "C" void kernel_launch(void* const* d_in, const int* in_sizes, int n_in,
                              void* d_out, int out_size, void* d_ws, size_t ws_size,
                              hipStream_t stream) {
    const float* x    = (const float*)d_in[0];
    const int*   row  = (const int*)  d_in[1];
    const int*   col  = (const int*)  d_in[2];
    const float* vals = (const float*)d_in[3];
    const float* W1   = (const float*)d_in[4];
    const float* W2   = (const float*)d_in[5];
    float* out = (float*)d_out;

    // workspace layout (256B-aligned chunks)
    char* ws = (char*)d_ws;
    auto align = [](size_t v) { return (v + 255) & ~(size_t)255; };
    int*      counts  = (int*)ws;              ws += align(sizeof(int) * N_NODES);
    uint32_t* ell     = (uint32_t*)ws;         ws += align(sizeof(uint32_t) * N_NODES * ELL_CAP);
    uint32_t* tpk     = (uint32_t*)ws;         ws += align(sizeof(uint32_t) * N_NODES * 64);
    uint32_t* hpk     = (uint32_t*)ws;         ws += align(sizeof(uint32_t) * N_NODES * 64);
    unsigned short* wt1 = (unsigned short*)ws; ws += align(sizeof(short) * 128 * 128);
    unsigned short* wt2 = (unsigned short*)ws; ws += align(sizeof(short) * 64 * 128);

    // ---- build: init + single-pass ELL scatter ----
    zero_convert<<<(N_NODES + 128 * 128 + 64 * 128 + 255) / 256, 256, 0, stream>>>(counts, W1, W2, wt1, wt2);
    scatter_ell<<<SCAT_BLOCKS_PER_XCD * XCD_GROUPS, 256, 0, stream>>>(row, col, vals, counts, ell);

    // ---- layer 1: t1 = bf16(x @ W1); h = bf16(relu(A @ t1)) ----
    gemm_mfma<HID_DIM, true><<<dim3(196, 2), 256, 0, stream>>>(x, nullptr, wt1, (unsigned short*)tpk);
    spmm_bf16_128<true><<<(N_NODES + 3) / 4, 256, 0, stream>>>(counts, ell, tpk, hpk);

    // ---- layer 2: t2 = bf16(h @ W2); out = A @ t2 ----
    gemm_mfma<OUT_DIM, false><<<dim3(196, 1), 256, 0, stream>>>(nullptr, hpk, wt2, (unsigned short*)tpk);
    spmm_bf16_64<<<(N_NODES + 3) / 4, 256, 0, stream>>>(counts, ell, tpk, out);
}